// Round 1
// baseline (1173.481 us; speedup 1.0000x reference)
//
#include <hip/hip_runtime.h>
#include <math.h>

#define Bdim 256
#define Sdim 512
#define Hdim 1024
#define Wdim 64
#define BK 64

// Kernel 1: scores GEMM.  grid = (16 j-tiles, 256 b), block = 256.
// Computes ws_scores[jt][b][w] = sum over this block's 64 j's of
//   v[j]*tanh( hc[b]·W1[j] + Mt[b,w]·W2[j] + b_attn[j] )
__global__ __launch_bounds__(256, 4) void k_scores(
    const float* __restrict__ inputs, const float* __restrict__ hc,
    const float* __restrict__ Wa, const float* __restrict__ ba,
    const float* __restrict__ v, const int* __restrict__ slen,
    float* __restrict__ ws_scores)
{
  const int jt = blockIdx.x;           // 0..15
  const int b  = blockIdx.y;           // 0..255
  const int t  = threadIdx.x;          // 0..255
  const int sl = slen[b];
  const int row0 = b * Sdim + sl - Wdim;   // first Mt row in inputs

  __shared__ float As[BK][64];   // Mt chunk,  [k][w]
  __shared__ float Bs[BK][64];   // W2 chunk,  [k][j]
  __shared__ float hcp[4][64];   // hc@W1^T partials
  __shared__ float red[16][64];  // score reduction

  // ---- inline hc @ W1^T for this j-tile (1.5% of total FLOPs) ----
  {
    const int j = t & 63, part = t >> 6;          // 4 k-partitions of 256
    const float* w1 = Wa + (size_t)(jt * 64 + j) * (2 * Hdim);
    const float* hr = hc + (size_t)b * Hdim;
    float s = 0.f;
    #pragma unroll 4
    for (int k = part * 256; k < part * 256 + 256; ++k)
      s = fmaf(hr[k], w1[k], s);
    hcp[part][j] = s;
  }

  const int w0 = (t & 15) * 4;   // thread's 4 w's
  const int j0 = (t >> 4) * 4;   // thread's 4 j's
  const int kq = t & 15;         // staging: k-quad
  const int wg = t >> 4;         // staging: row group of 4
  float acc[4][4] = {{0.f}};

  for (int k0 = 0; k0 < Hdim; k0 += BK) {
    // global loads first (overlap with previous chunk's compute)
    float4 la[4], lb[4];
    #pragma unroll
    for (int q = 0; q < 4; ++q) {
      la[q] = *(const float4*)(inputs + (size_t)(row0 + wg * 4 + q) * Hdim + k0 + kq * 4);
      lb[q] = *(const float4*)(Wa + (size_t)(jt * 64 + wg * 4 + q) * (2 * Hdim) + Hdim + k0 + kq * 4);
    }
    __syncthreads();
    // register-transpose -> [k][w] layout, b128 stores
    #pragma unroll
    for (int c = 0; c < 4; ++c) {
      *(float4*)&As[kq * 4 + c][wg * 4] =
        make_float4(((float*)&la[0])[c], ((float*)&la[1])[c],
                    ((float*)&la[2])[c], ((float*)&la[3])[c]);
      *(float4*)&Bs[kq * 4 + c][wg * 4] =
        make_float4(((float*)&lb[0])[c], ((float*)&lb[1])[c],
                    ((float*)&lb[2])[c], ((float*)&lb[3])[c]);
    }
    __syncthreads();
    #pragma unroll 8
    for (int k = 0; k < BK; ++k) {
      const float4 a  = *(const float4*)&As[k][w0];
      const float4 bb = *(const float4*)&Bs[k][j0];
      const float av[4] = {a.x, a.y, a.z, a.w};
      const float bv[4] = {bb.x, bb.y, bb.z, bb.w};
      #pragma unroll
      for (int wi = 0; wi < 4; ++wi)
        #pragma unroll
        for (int ji = 0; ji < 4; ++ji)
          acc[wi][ji] = fmaf(av[wi], bv[ji], acc[wi][ji]);
    }
  }

  // ---- epilogue: + hcW + bias, tanh, dot with v ----
  float sloc[4] = {0.f, 0.f, 0.f, 0.f};
  #pragma unroll
  for (int ji = 0; ji < 4; ++ji) {
    const int jg = jt * 64 + j0 + ji;
    const float hw = hcp[0][j0 + ji] + hcp[1][j0 + ji] +
                     hcp[2][j0 + ji] + hcp[3][j0 + ji] + ba[jg];
    const float vj = v[jg];
    #pragma unroll
    for (int wi = 0; wi < 4; ++wi) {
      const float e = tanhf(acc[wi][ji] + hw);
      sloc[wi] = fmaf(vj, e, sloc[wi]);
    }
  }
  #pragma unroll
  for (int wi = 0; wi < 4; ++wi) red[wg][w0 + wi] = sloc[wi];
  __syncthreads();
  if (t < 64) {
    float s = 0.f;
    #pragma unroll
    for (int p = 0; p < 16; ++p) s += red[p][t];
    ws_scores[(size_t)jt * (Bdim * Wdim) + b * Wdim + t] = s;
  }
}

// Kernel 2: softmax over W=64 (one wave), context, par.  grid = 256 (b).
__global__ __launch_bounds__(256) void k_finish(
    const float* __restrict__ inputs, const int* __restrict__ slen,
    const int* __restrict__ parent, const float* __restrict__ ws_scores,
    float* __restrict__ out)
{
  const int b = blockIdx.x;
  const int t = threadIdx.x;
  const int sl = slen[b];
  __shared__ float attn[64];

  if (t < 64) {   // exactly wave 0
    float s = 0.f;
    #pragma unroll
    for (int p = 0; p < 16; ++p)
      s += ws_scores[(size_t)p * (Bdim * Wdim) + b * Wdim + t];
    float mx = s;
    #pragma unroll
    for (int off = 32; off > 0; off >>= 1) mx = fmaxf(mx, __shfl_xor(mx, off));
    const float e = __expf(s - mx);
    float sm = e;
    #pragma unroll
    for (int off = 32; off > 0; off >>= 1) sm += __shfl_xor(sm, off);
    const float a = e / sm;
    out[b * Wdim + t] = a;     // output 0: attn_weights (B,1,W)
    attn[t] = a;
  }
  __syncthreads();

  // context[b,h] = sum_w attn[w] * Mt[b,w,h]
  const float* base = inputs + (size_t)(b * Sdim + sl - Wdim) * Hdim;
  float a0 = 0.f, a1 = 0.f, a2 = 0.f, a3 = 0.f;
  for (int w = 0; w < Wdim; ++w) {
    const float aw = attn[w];
    const float* r = base + (size_t)w * Hdim;
    a0 = fmaf(aw, r[t], a0);
    a1 = fmaf(aw, r[t + 256], a1);
    a2 = fmaf(aw, r[t + 512], a2);
    a3 = fmaf(aw, r[t + 768], a3);
  }
  float* ctx = out + Bdim * Wdim + (size_t)b * Hdim;   // output 1: context (B,1,H)
  ctx[t] = a0; ctx[t + 256] = a1; ctx[t + 512] = a2; ctx[t + 768] = a3;

  // output 2: par (B,H) — row gather, float4 copy
  const float4* pr = (const float4*)(inputs + (size_t)(b * Sdim + sl - parent[b] - 1) * Hdim);
  float4* po = (float4*)(out + Bdim * Wdim + Bdim * Hdim + (size_t)b * Hdim);
  po[t] = pr[t];
}

extern "C" void kernel_launch(void* const* d_in, const int* in_sizes, int n_in,
                              void* d_out, int out_size, void* d_ws, size_t ws_size,
                              hipStream_t stream) {
  const float* inputs = (const float*)d_in[0];
  const float* hc     = (const float*)d_in[1];
  const float* Wa     = (const float*)d_in[2];
  const float* ba     = (const float*)d_in[3];
  const float* v      = (const float*)d_in[4];
  const int*   slen   = (const int*)d_in[5];
  const int*   parent = (const int*)d_in[6];
  float* out = (float*)d_out;
  float* ws  = (float*)d_ws;   // needs 16*256*64*4 = 1 MiB

  dim3 g1(16, 256);
  k_scores<<<g1, 256, 0, stream>>>(inputs, hc, Wa, ba, v, slen, ws);
  k_finish<<<256, 256, 0, stream>>>(inputs, slen, parent, ws, out);
}

// Round 2
// 1040.618 us; speedup vs baseline: 1.1277x; 1.1277x over previous
//
#include <hip/hip_runtime.h>
#include <math.h>

#define Bdim 256
#define Sdim 512
#define Hdim 1024
#define Wdim 64
#define BK 32
#define JTILE 256   // j's per block
#define NJT 4       // number of j tiles

// Kernel 1: scores GEMM. grid = (4 j-tiles, 256 b), block = 256 (8 tw x 32 tj),
// each thread owns an 8w x 8j accumulator.
// ws_scores[jt][b][w] = sum over this tile's 256 j of
//   v[j]*tanh( hc[b]·W1[j] + Mt[b,w]·W2[j] + b_attn[j] )
__global__ __launch_bounds__(256, 2) void k_scores(
    const float* __restrict__ inputs, const float* __restrict__ hc,
    const float* __restrict__ Wa, const float* __restrict__ ba,
    const float* __restrict__ v, const int* __restrict__ slen,
    float* __restrict__ ws_scores)
{
  const int jt = blockIdx.x;           // 0..3
  const int b  = blockIdx.y;           // 0..255
  const int t  = threadIdx.x;          // 0..255
  const int sl = slen[b];
  const long row0 = (long)b * Sdim + sl - Wdim;

  // As: [BK][64] = 8 KB  |  Bs: [BK][256] = 32 KB   (total 40 KB)
  __shared__ float smem[BK * 64 + BK * JTILE];
  float (*As)[64]    = (float(*)[64])smem;
  float (*Bs)[JTILE] = (float(*)[JTILE])(smem + BK * 64);

  const int tw = t & 7;        // 8 w-groups
  const int tj = t >> 3;       // 32 j-groups
  const int w0 = tw * 8;
  const int j0 = tj * 8;

  // staging mapping
  const int aw  = t & 63;      // As: which w row
  const int akg = t >> 6;      // As: k-group of 8
  const float* arow = inputs + (row0 + aw) * Hdim;
  const float* brow = Wa + (size_t)(jt * JTILE + t) * (2 * Hdim) + Hdim;  // W2 row j

  float acc[8][8] = {{0.f}};

  for (int k0 = 0; k0 < Hdim; k0 += BK) {
    // ---- global loads (before sync: overlap previous tile's compute) ----
    float4 a0 = *(const float4*)(arow + k0 + akg * 8);
    float4 a1 = *(const float4*)(arow + k0 + akg * 8 + 4);
    float4 bld[8];
    #pragma unroll
    for (int q = 0; q < 8; ++q)
      bld[q] = *(const float4*)(brow + k0 + q * 4);

    __syncthreads();
    // ---- transposed stores: [k][w] / [k][j]; lanes consecutive -> 2-way (free)
    #pragma unroll
    for (int c = 0; c < 4; ++c) {
      As[akg * 8 + c][aw]     = ((const float*)&a0)[c];
      As[akg * 8 + 4 + c][aw] = ((const float*)&a1)[c];
    }
    #pragma unroll
    for (int q = 0; q < 8; ++q)
      #pragma unroll
      for (int c = 0; c < 4; ++c)
        Bs[q * 4 + c][t] = ((const float*)&bld[q])[c];
    __syncthreads();

    // ---- compute: per k, 4x ds_read_b128 feed 64 FMA ----
    #pragma unroll 8
    for (int k = 0; k < BK; ++k) {
      const float4 av0 = *(const float4*)&As[k][w0];
      const float4 av1 = *(const float4*)&As[k][w0 + 4];
      const float4 bv0 = *(const float4*)&Bs[k][j0];
      const float4 bv1 = *(const float4*)&Bs[k][j0 + 4];
      const float A[8]  = {av0.x, av0.y, av0.z, av0.w, av1.x, av1.y, av1.z, av1.w};
      const float Bv[8] = {bv0.x, bv0.y, bv0.z, bv0.w, bv1.x, bv1.y, bv1.z, bv1.w};
      #pragma unroll
      for (int wi = 0; wi < 8; ++wi)
        #pragma unroll
        for (int ji = 0; ji < 8; ++ji)
          acc[wi][ji] = fmaf(A[wi], Bv[ji], acc[wi][ji]);
    }
  }

  // ---- hc @ W1^T for this tile's 256 j (reuses Bs region) ----
  __syncthreads();
  float* hcw = (float*)Bs;   // 256 floats
  {
    const float* w1 = Wa + (size_t)(jt * JTILE + t) * (2 * Hdim);
    const float* hr = hc + (size_t)b * Hdim;
    float s = 0.f;
    #pragma unroll 4
    for (int k = 0; k < Hdim; k += 4) {
      const float4 hv = *(const float4*)(hr + k);
      const float4 wv = *(const float4*)(w1 + k);
      s = fmaf(hv.x, wv.x, s); s = fmaf(hv.y, wv.y, s);
      s = fmaf(hv.z, wv.z, s); s = fmaf(hv.w, wv.w, s);
    }
    hcw[t] = s + ba[jt * JTILE + t];
  }
  __syncthreads();

  // ---- epilogue: tanh + v-dot, partials into As region ----
  float sloc[8] = {0.f, 0.f, 0.f, 0.f, 0.f, 0.f, 0.f, 0.f};
  #pragma unroll
  for (int ji = 0; ji < 8; ++ji) {
    const float hw = hcw[j0 + ji];
    const float vj = v[jt * JTILE + j0 + ji];
    #pragma unroll
    for (int wi = 0; wi < 8; ++wi)
      sloc[wi] = fmaf(vj, tanhf(acc[wi][ji] + hw), sloc[wi]);
  }
  float (*red)[64] = (float(*)[64])smem;   // 32 x 64, aliases As
  #pragma unroll
  for (int wi = 0; wi < 8; ++wi) red[tj][w0 + wi] = sloc[wi];
  __syncthreads();
  if (t < 64) {
    float s = 0.f;
    #pragma unroll
    for (int p = 0; p < 32; ++p) s += red[p][t];
    ws_scores[(size_t)jt * (Bdim * Wdim) + b * Wdim + t] = s;
  }
}

// Kernel 2: softmax (W=64, one wave) + context + par.
// grid = (256 b, 4 h-chunks), block = 256. Softmax recomputed per chunk (cheap).
__global__ __launch_bounds__(256) void k_finish(
    const float* __restrict__ inputs, const int* __restrict__ slen,
    const int* __restrict__ parent, const float* __restrict__ ws_scores,
    float* __restrict__ out)
{
  const int b = blockIdx.x;
  const int c = blockIdx.y;          // h-chunk: 256 h's
  const int t = threadIdx.x;
  const int sl = slen[b];
  __shared__ float attn[64];

  if (t < 64) {   // exactly wave 0
    float s = ws_scores[b * Wdim + t]
            + ws_scores[1 * (Bdim * Wdim) + b * Wdim + t]
            + ws_scores[2 * (Bdim * Wdim) + b * Wdim + t]
            + ws_scores[3 * (Bdim * Wdim) + b * Wdim + t];
    float mx = s;
    #pragma unroll
    for (int off = 32; off > 0; off >>= 1) mx = fmaxf(mx, __shfl_xor(mx, off));
    const float e = __expf(s - mx);
    float sm = e;
    #pragma unroll
    for (int off = 32; off > 0; off >>= 1) sm += __shfl_xor(sm, off);
    const float a = e / sm;
    if (c == 0) out[b * Wdim + t] = a;     // output 0: attn (B,1,W)
    attn[t] = a;
  }
  __syncthreads();

  // context[b, c*256 + t]
  const float* base = inputs + ((size_t)b * Sdim + sl - Wdim) * Hdim + c * 256;
  float a0 = 0.f;
  #pragma unroll 8
  for (int w = 0; w < Wdim; ++w)
    a0 = fmaf(attn[w], base[(size_t)w * Hdim + t], a0);
  out[Bdim * Wdim + (size_t)b * Hdim + c * 256 + t] = a0;   // output 1: context

  // output 2: par (B,H)
  const float* pr = inputs + ((size_t)b * Sdim + sl - parent[b] - 1) * Hdim + c * 256;
  out[Bdim * Wdim + Bdim * Hdim + (size_t)b * Hdim + c * 256 + t] = pr[t];
}

extern "C" void kernel_launch(void* const* d_in, const int* in_sizes, int n_in,
                              void* d_out, int out_size, void* d_ws, size_t ws_size,
                              hipStream_t stream) {
  const float* inputs = (const float*)d_in[0];
  const float* hc     = (const float*)d_in[1];
  const float* Wa     = (const float*)d_in[2];
  const float* ba     = (const float*)d_in[3];
  const float* v      = (const float*)d_in[4];
  const int*   slen   = (const int*)d_in[5];
  const int*   parent = (const int*)d_in[6];
  float* out = (float*)d_out;
  float* ws  = (float*)d_ws;   // needs 4*256*64*4 = 256 KiB

  dim3 g1(NJT, Bdim);
  k_scores<<<g1, 256, 0, stream>>>(inputs, hc, Wa, ba, v, slen, ws);
  dim3 g2(Bdim, 4);
  k_finish<<<g2, 256, 0, stream>>>(inputs, slen, parent, ws, out);
}